// Round 1
// baseline (655.891 us; speedup 1.0000x reference)
//
#include <hip/hip_runtime.h>
#include <cstdint>
#include <cstddef>

#define DEVFN static __device__ __forceinline__

typedef __attribute__((ext_vector_type(4))) float f32x4;
typedef __attribute__((ext_vector_type(8))) __bf16 bf16x8;

typedef __attribute__((address_space(1))) void gvoid;
typedef __attribute__((address_space(3))) void svoid;

DEVFN unsigned short f32_to_bf16_bits(float f) {
  uint32_t u = __builtin_bit_cast(uint32_t, f);
  return (unsigned short)((u + 0x7fffu + ((u >> 16) & 1u)) >> 16);
}
DEVFN float bf16_bits_to_f32(unsigned short s) {
  return __builtin_bit_cast(float, (uint32_t)s << 16);
}

// global -> LDS direct copy, 16B per lane. LDS base must be wave-uniform.
DEVFN void load_lds16(const unsigned short* g, unsigned short* l) {
  __builtin_amdgcn_global_load_lds((gvoid*)g, (svoid*)l, 16, 0, 0);
}

// ---------------- fp32 -> bf16 conversion (8 elems/thread) ----------------
__global__ __launch_bounds__(256) void cvt_f32_bf16(const float* __restrict__ in,
                                                    unsigned short* __restrict__ out,
                                                    int n8) {
  int i = (int)(blockIdx.x * 256 + threadIdx.x);
  if (i >= n8) return;
  const float4* p = (const float4*)in;
  float4 a = p[2 * i], b = p[2 * i + 1];
  union { unsigned short s[8]; uint4 v; } o;
  o.s[0] = f32_to_bf16_bits(a.x); o.s[1] = f32_to_bf16_bits(a.y);
  o.s[2] = f32_to_bf16_bits(a.z); o.s[3] = f32_to_bf16_bits(a.w);
  o.s[4] = f32_to_bf16_bits(b.x); o.s[5] = f32_to_bf16_bits(b.y);
  o.s[6] = f32_to_bf16_bits(b.z); o.s[7] = f32_to_bf16_bits(b.w);
  ((uint4*)out)[i] = o.v;
}

// WkT[h][j][d] = Wk[h*64+d][j]   (8*512*64 = 262144 elems)
__global__ __launch_bounds__(256) void wkt_kernel(const float* __restrict__ Wk,
                                                  unsigned short* __restrict__ WkT) {
  int idx = (int)(blockIdx.x * 256 + threadIdx.x);
  int d = idx & 63;
  int j = (idx >> 6) & 511;
  int h = idx >> 15;
  WkT[idx] = f32_to_bf16_bits(Wk[((h << 6) + d) * 512 + j]);
}

// ---------------- bf16 MFMA GEMM, B given transposed (Bt[n][k]) ----------------
// C[m][n] = sum_k A[m][k] * Bt[n][k]  (+bias[n]) (+res[m][n]) (relu) -> bf16|f32
// BM=128, BK=32, 4 waves in 2x2, wave tile 64 x (BN/2).
template<int BN, bool OUT_BF16, bool RELU, bool ADD_RES>
__global__ __launch_bounds__(256)
void gemm_bt(const unsigned short* __restrict__ A, int lda, long long zA,
             const unsigned short* __restrict__ Bt, int ldb, long long zB,
             void* __restrict__ Cv, int ldc, long long zC,
             const float* __restrict__ bias, int zBias,
             const float* __restrict__ res, int ldres,
             int K) {
  constexpr int BM = 128;
  constexpr int WN = BN / 2;   // 64 or 32
  constexpr int NT = WN / 16;  // 4 or 2
  __shared__ __align__(16) unsigned short As[BM * 32];
  __shared__ __align__(16) unsigned short Bs[BN * 32];

  const int tid = (int)threadIdx.x;
  const int lane = tid & 63;
  const int w = tid >> 6;
  const int wm = w >> 1;
  const int wn = w & 1;
  const int m0 = (int)blockIdx.y * BM;
  const int n0 = (int)blockIdx.x * BN;
  const long long z = (long long)blockIdx.z;

  A += z * zA;
  Bt += z * zB;
  const float* biasz = bias ? (bias + z * zBias) : nullptr;

  f32x4 acc[4][NT];
#pragma unroll
  for (int i = 0; i < 4; ++i)
#pragma unroll
    for (int j = 0; j < NT; ++j) acc[i][j] = f32x4{0.f, 0.f, 0.f, 0.f};

  // staging geometry: per wave 1KB per issue; byte offset o -> row o/64, k-elem (o&63)/2
  const int o0 = w * 1024 + lane * 16;
  const int r0 = o0 >> 6, c0 = (o0 & 63) >> 1;
  const int o1 = o0 + 4096;
  const int r1 = o1 >> 6, c1 = (o1 & 63) >> 1;

  const int kIters = K / 32;
  for (int kt = 0; kt < kIters; ++kt) {
    const int k0 = kt * 32;
    __syncthreads();
    load_lds16(A + (size_t)(m0 + r0) * lda + (k0 + c0), As + w * 512);
    load_lds16(A + (size_t)(m0 + r1) * lda + (k0 + c1), As + 2048 + w * 512);
    if (BN == 128) {
      load_lds16(Bt + (size_t)(n0 + r0) * ldb + (k0 + c0), Bs + w * 512);
      load_lds16(Bt + (size_t)(n0 + r1) * ldb + (k0 + c1), Bs + 2048 + w * 512);
    } else {
      load_lds16(Bt + (size_t)(n0 + r0) * ldb + (k0 + c0), Bs + w * 512);
    }
    asm volatile("s_waitcnt vmcnt(0)" ::: "memory");
    __syncthreads();

    const int fr = lane & 15;
    const int kq = lane >> 4;
    bf16x8 af[4], bf[NT];
#pragma unroll
    for (int i = 0; i < 4; ++i) {
      const int m = wm * 64 + i * 16 + fr;
      af[i] = __builtin_bit_cast(bf16x8, *(const uint4*)(As + m * 32 + kq * 8));
    }
#pragma unroll
    for (int j = 0; j < NT; ++j) {
      const int n = wn * WN + j * 16 + fr;
      bf[j] = __builtin_bit_cast(bf16x8, *(const uint4*)(Bs + n * 32 + kq * 8));
    }
#pragma unroll
    for (int i = 0; i < 4; ++i)
#pragma unroll
      for (int j = 0; j < NT; ++j)
        acc[i][j] = __builtin_amdgcn_mfma_f32_16x16x32_bf16(af[i], bf[j], acc[i][j], 0, 0, 0);
  }

  // epilogue: C/D layout col=lane&15, row=(lane>>4)*4+reg (HW-verified mapping)
  const int fr = lane & 15;
  const int rq = lane >> 4;
  unsigned short* Cb = (unsigned short*)Cv + z * zC;
  float* Cf = (float*)Cv + z * zC;
#pragma unroll
  for (int i = 0; i < 4; ++i) {
    const int rbase = m0 + wm * 64 + i * 16 + rq * 4;
#pragma unroll
    for (int j = 0; j < NT; ++j) {
      const int col = n0 + wn * WN + j * 16 + fr;
      const float bvv = biasz ? biasz[col] : 0.f;
#pragma unroll
      for (int r = 0; r < 4; ++r) {
        float v = acc[i][j][r] + bvv;
        if (ADD_RES) v += res[(size_t)(rbase + r) * ldres + col];
        if (RELU) v = fmaxf(v, 0.f);
        if (OUT_BF16) Cb[(size_t)(rbase + r) * ldc + col] = f32_to_bf16_bits(v);
        else Cf[(size_t)(rbase + r) * ldc + col] = v;
      }
    }
  }
}

// ---------------- fused scores/softmax/vbar (in-place U -> vbar) ----------------
// Per block: one token n. s[h,c] = U[n,h,:]. key[n*8+c,:] / 8; softmax over c;
// vbar[n,h,:] = sum_c att[c] * value[n*8+c,:]  (written over U, bf16)
__global__ __launch_bounds__(256) void attn_kernel(const float* __restrict__ key,
                                                   const float* __restrict__ value,
                                                   unsigned short* __restrict__ U) {
  __shared__ float kf[8 * 512];
  __shared__ float vf[8 * 512];
  const int n = (int)blockIdx.x;
  const int tid = (int)threadIdx.x;
  const int lane = tid & 63;
  const int w = tid >> 6;

  const float* kg = key + (size_t)n * 4096;
  const float* vg = value + (size_t)n * 4096;
#pragma unroll
  for (int t = 0; t < 4; ++t) {
    int i = (t * 256 + tid) * 4;
    *(float4*)(kf + i) = *(const float4*)(kg + i);
    *(float4*)(vf + i) = *(const float4*)(vg + i);
  }
  __syncthreads();

  unsigned short* Un = U + (size_t)n * 4096;
#pragma unroll
  for (int hh = 0; hh < 2; ++hh) {
    const int h = w * 2 + hh;
    float u[8];
#pragma unroll
    for (int t = 0; t < 8; ++t) u[t] = bf16_bits_to_f32(Un[h * 512 + lane + 64 * t]);

    float zc[8];
    float zmax = -1e30f;
#pragma unroll
    for (int c = 0; c < 8; ++c) {
      float p = 0.f;
#pragma unroll
      for (int t = 0; t < 8; ++t) p += u[t] * kf[c * 512 + lane + 64 * t];
#pragma unroll
      for (int off = 32; off > 0; off >>= 1) p += __shfl_xor(p, off, 64);
      zc[c] = p * 0.125f;  // / sqrt(64)
      zmax = fmaxf(zmax, zc[c]);
    }
    float se = 0.f;
#pragma unroll
    for (int c = 0; c < 8; ++c) { zc[c] = __expf(zc[c] - zmax); se += zc[c]; }
    const float inv = 1.f / se;
#pragma unroll
    for (int t = 0; t < 8; ++t) {
      const int j = lane + 64 * t;
      float a = 0.f;
#pragma unroll
      for (int c = 0; c < 8; ++c) a += (zc[c] * inv) * vf[c * 512 + j];
      Un[h * 512 + j] = f32_to_bf16_bits(a);
    }
  }
}

// ---------------- LayerNorm over rows of 512; wave per row ----------------
__global__ __launch_bounds__(256) void ln_kernel(const float* __restrict__ in,
                                                 const float* __restrict__ g,
                                                 const float* __restrict__ b,
                                                 float* __restrict__ outf,
                                                 unsigned short* __restrict__ outb) {
  const int lane = (int)threadIdx.x & 63;
  const size_t row = (size_t)blockIdx.x * 4 + (threadIdx.x >> 6);
  const int col = lane * 8;
  const float* x = in + row * 512;
  float4 a0 = *(const float4*)(x + col);
  float4 a1 = *(const float4*)(x + col + 4);
  float v[8] = {a0.x, a0.y, a0.z, a0.w, a1.x, a1.y, a1.z, a1.w};
  float s = 0.f, sq = 0.f;
#pragma unroll
  for (int t = 0; t < 8; ++t) { s += v[t]; sq += v[t] * v[t]; }
#pragma unroll
  for (int off = 32; off > 0; off >>= 1) {
    s += __shfl_xor(s, off, 64);
    sq += __shfl_xor(sq, off, 64);
  }
  const float mean = s * (1.f / 512.f);
  const float var = sq * (1.f / 512.f) - mean * mean;
  const float rstd = rsqrtf(var + 1e-5f);
  float o[8];
#pragma unroll
  for (int t = 0; t < 8; ++t) o[t] = (v[t] - mean) * rstd * g[col + t] + b[col + t];
  if (outf) {
    *(float4*)(outf + row * 512 + col) = make_float4(o[0], o[1], o[2], o[3]);
    *(float4*)(outf + row * 512 + col + 4) = make_float4(o[4], o[5], o[6], o[7]);
  }
  if (outb) {
    union { unsigned short s_[8]; uint4 v_; } u;
#pragma unroll
    for (int t = 0; t < 8; ++t) u.s_[t] = f32_to_bf16_bits(o[t]);
    *(uint4*)(outb + row * 512 + col) = u.v_;
  }
}

extern "C" void kernel_launch(void* const* d_in, const int* in_sizes, int n_in,
                              void* d_out, int out_size, void* d_ws, size_t ws_size,
                              hipStream_t stream) {
  const float* query = (const float*)d_in[0];
  const float* key   = (const float*)d_in[1];
  const float* value = (const float*)d_in[2];
  const float* Wq = (const float*)d_in[3];
  const float* bq = (const float*)d_in[4];
  const float* Wk = (const float*)d_in[5];
  // bk (d_in[6]) cancels exactly in the softmax -> unused
  const float* Wv = (const float*)d_in[7];
  const float* bv = (const float*)d_in[8];
  const float* Wo = (const float*)d_in[9];
  const float* bo = (const float*)d_in[10];
  const float* ln1g = (const float*)d_in[11];
  const float* ln1b = (const float*)d_in[12];
  const float* W1 = (const float*)d_in[13];
  const float* b1 = (const float*)d_in[14];
  const float* W2 = (const float*)d_in[15];
  const float* b2 = (const float*)d_in[16];
  const float* ln2g = (const float*)d_in[17];
  const float* ln2b = (const float*)d_in[18];
  float* out = (float*)d_out;

  char* ws = (char*)d_ws;
  size_t off = 0;
  auto alloc = [&](size_t bytes) -> void* {
    off = (off + 255) & ~(size_t)255;
    void* p = ws + off;
    off += bytes;
    return p;
  };

  const int N = 8192;  // tokens = F*B
  unsigned short* qb   = (unsigned short*)alloc((size_t)N * 512 * 2);
  unsigned short* Wqb  = (unsigned short*)alloc(512 * 512 * 2);
  unsigned short* Wvb  = (unsigned short*)alloc(512 * 512 * 2);
  unsigned short* Wob  = (unsigned short*)alloc(512 * 512 * 2);
  unsigned short* W1b  = (unsigned short*)alloc(1024 * 512 * 2);
  unsigned short* W2b  = (unsigned short*)alloc(512 * 1024 * 2);
  unsigned short* WkT  = (unsigned short*)alloc(8 * 512 * 64 * 2);
  unsigned short* Qp   = (unsigned short*)alloc((size_t)N * 512 * 2);   // later reused as x
  unsigned short* U    = (unsigned short*)alloc((size_t)N * 4096 * 2);  // U, then vbar in-place
  float*          h1pre= (float*)alloc((size_t)N * 512 * 4);            // later reused as o2pre
  unsigned short* h1b  = (unsigned short*)alloc((size_t)N * 512 * 2);
  float*          h1f  = (float*)alloc((size_t)N * 512 * 4);
  unsigned short* mid  = (unsigned short*)alloc((size_t)N * 1024 * 2);
  unsigned short* x    = Qp;       // reuse (Qp dead after U-GEMM)
  float*          o2pre= h1pre;    // reuse (raw pre-LN1 dead after LN1)
  (void)ws_size; (void)in_sizes; (void)n_in; (void)out_size;

  dim3 blk(256);
  // conversions
  cvt_f32_bf16<<<2048, blk, 0, stream>>>(query, qb, N * 512 / 8);
  cvt_f32_bf16<<<128, blk, 0, stream>>>(Wq, Wqb, 512 * 512 / 8);
  cvt_f32_bf16<<<128, blk, 0, stream>>>(Wv, Wvb, 512 * 512 / 8);
  cvt_f32_bf16<<<128, blk, 0, stream>>>(Wo, Wob, 512 * 512 / 8);
  cvt_f32_bf16<<<256, blk, 0, stream>>>(W1, W1b, 1024 * 512 / 8);
  cvt_f32_bf16<<<256, blk, 0, stream>>>(W2, W2b, 512 * 1024 / 8);
  wkt_kernel<<<1024, blk, 0, stream>>>(Wk, WkT);

  // Qp = qb @ Wq^T + bq            [8192 x 512], bf16
  gemm_bt<128, true, false, false><<<dim3(4, 64, 1), blk, 0, stream>>>(
      qb, 512, 0, Wqb, 512, 0, Qp, 512, 0, bq, 0, nullptr, 0, 512);
  // U[n, h*512+j] = Qp[n, h*64:..] @ WkT[h]   (K=64 per head, grid.z = head)
  gemm_bt<128, true, false, false><<<dim3(4, 64, 8), blk, 0, stream>>>(
      Qp, 512, 64, WkT, 64, 32768, U, 4096, 512, nullptr, 0, nullptr, 0, 64);
  // scores + softmax + vbar (in place over U)
  attn_kernel<<<8192, blk, 0, stream>>>(key, value, U);
  // x[n, h*64+d] = vbar[n,h,:] @ Wv_head^T + bv_head   (N=64 per head)
  gemm_bt<64, true, false, false><<<dim3(1, 64, 8), blk, 0, stream>>>(
      U, 4096, 512, Wvb, 512, 32768, x, 512, 64, bv, 64, nullptr, 0, 512);
  // h1pre = x @ Wo^T + bo + query   (fp32)
  gemm_bt<128, false, false, true><<<dim3(4, 64, 1), blk, 0, stream>>>(
      x, 512, 0, Wob, 512, 0, h1pre, 512, 0, bo, 0, query, 512, 512);
  // h1 = LN(h1pre) -> h1f (fp32 residual) + h1b (bf16 GEMM input)
  ln_kernel<<<2048, blk, 0, stream>>>(h1pre, ln1g, ln1b, h1f, h1b);
  // mid = relu(h1 @ W1^T + b1)      [8192 x 1024], bf16
  gemm_bt<128, true, true, false><<<dim3(8, 64, 1), blk, 0, stream>>>(
      h1b, 512, 0, W1b, 512, 0, mid, 1024, 0, b1, 0, nullptr, 0, 512);
  // o2pre = mid @ W2^T + b2 + h1    (fp32)
  gemm_bt<128, false, false, true><<<dim3(4, 64, 1), blk, 0, stream>>>(
      mid, 1024, 0, W2b, 1024, 0, o2pre, 512, 0, b2, 0, h1f, 512, 1024);
  // out = LN(o2pre)
  ln_kernel<<<2048, blk, 0, stream>>>(o2pre, ln2g, ln2b, out, nullptr);
}